// Round 4
// baseline (891.981 us; speedup 1.0000x reference)
//
#include <hip/hip_runtime.h>
#include <stdint.h>

#define B_    64
#define CIN   64
#define L_IN  16384
#define COUT  128
#define K_    7
#define LPAD  3
#define LPA   16416             // padded row stride for A (uint64 words per b)
#define AMARGIN 512             // tail margin words so last-block reads stay in-bounds
#define LOUT  8189              // pooled output length
#define OB    112               // pooled outputs per block (x-dim)
#define NXB   74                // ceil(8189/112)
#define CSTR  236               // int16 per cout row (118 dwords = 22 mod 32 -> ~2-way banks)

typedef int v4i __attribute__((ext_vector_type(4)));

// ---------------- pack A: sign bits of I along Cin into uint64 ----------------
// A[b][l]: bit ci = 1 iff value < 0. Pad positions (value -1.0) = all ones.
__global__ __launch_bounds__(256) void pack_A(const float* __restrict__ I,
                                              uint64_t* __restrict__ A) {
    int b     = blockIdx.x >> 4;     // 16 blocks per b
    int chunk = blockIdx.x & 15;
    int t     = threadIdx.x;
    int l0    = chunk * 1024 + t * 4;
    const uint32_t* Ib = (const uint32_t*)(I + (size_t)b * CIN * L_IN + l0);
    uint32_t lo0 = 0, lo1 = 0, lo2 = 0, lo3 = 0;
    uint32_t hi0 = 0, hi1 = 0, hi2 = 0, hi3 = 0;
#pragma unroll 8
    for (int ci = 0; ci < 32; ++ci) {
        uint4 v = *(const uint4*)(Ib + (size_t)ci * L_IN);
        lo0 |= (v.x >> 31) << ci;
        lo1 |= (v.y >> 31) << ci;
        lo2 |= (v.z >> 31) << ci;
        lo3 |= (v.w >> 31) << ci;
    }
#pragma unroll 8
    for (int ci = 0; ci < 32; ++ci) {
        uint4 v = *(const uint4*)(Ib + (size_t)(ci + 32) * L_IN);
        hi0 |= (v.x >> 31) << ci;
        hi1 |= (v.y >> 31) << ci;
        hi2 |= (v.z >> 31) << ci;
        hi3 |= (v.w >> 31) << ci;
    }
    uint64_t* Ab = A + (size_t)b * LPA + (LPAD + l0);
    Ab[0] = ((uint64_t)hi0 << 32) | lo0;
    Ab[1] = ((uint64_t)hi1 << 32) | lo1;
    Ab[2] = ((uint64_t)hi2 << 32) | lo2;
    Ab[3] = ((uint64_t)hi3 << 32) | lo3;
    // pad columns: p in {0,1,2, 16387,16388,16389} -> sign(-1.0) -> all ones
    if (chunk == 0 && t < 6) {
        int l = (t < 3) ? t : (L_IN + t);
        A[(size_t)b * LPA + l] = ~0ULL;
    }
}

// ---------------- pack W as int8 +/-1, layout [k][cout][ci] ----------------
__global__ __launch_bounds__(256) void pack_Wi8(const float* __restrict__ W,
                                                uint8_t* __restrict__ Wp) {
    int idx = blockIdx.x * 256 + threadIdx.x;
    if (idx >= COUT * K_) return;
    int k  = idx >> 7;        // 0..6
    int co = idx & 127;
    uint8_t* dst = Wp + ((size_t)k * COUT + co) * 64;
    uint32_t d[16];
#pragma unroll
    for (int ci4 = 0; ci4 < 16; ++ci4) {
        uint32_t dw = 0;
#pragma unroll
        for (int j = 0; j < 4; ++j) {
            int ci = ci4 * 4 + j;
            uint32_t s = __float_as_uint(W[(size_t)co * CIN * K_ + ci * K_ + k]) >> 31;
            dw |= (s ? 0xFFu : 0x01u) << (8 * j);
        }
        d[ci4] = dw;
    }
#pragma unroll
    for (int q = 0; q < 4; ++q)
        *(uint4*)(dst + q * 16) = make_uint4(d[4*q+0], d[4*q+1], d[4*q+2], d[4*q+3]);
}

// ---------------- main: i8-MFMA conv + maxpool(7,2) + threshold ----------------
// Block = 112 pooled outputs x 64 couts. No xs LDS: each lane expands its A-fragment
// in-register from the bit-packed A (one uint16 per (row, l4) -> 16 bytes +/-1).
// LDS = cs only (29.5 KB) -> 5 blocks/CU; single barrier.
__global__ __launch_bounds__(256, 5) void mfma_conv_pool(
    const uint64_t* __restrict__ A, const uint8_t* __restrict__ Wp,
    const float* __restrict__ tp_, const float* __restrict__ tm_,
    const float* __restrict__ ps_, const float* __restrict__ ms_,
    float* __restrict__ out)
{
    __shared__ __align__(16) int16_t cs[64 * CSTR];   // 30208 B

    const int bx = blockIdx.x, cy = blockIdx.y, b = blockIdx.z;
    const int t = threadIdx.x;
    const int lane = t & 63, w = t >> 6;
    const int l15 = lane & 15, l4 = lane >> 4;
    const int o0 = bx * OB;
    const int c0 = 2 * o0;          // first conv position this block needs
    const int cout0 = cy * 64;

    const uint16_t* ap = (const uint16_t*)(A + (size_t)b * LPA);

    // ---- conv: wave w owns c-tiles 4w..4w+3, processed as 2 halves of 2 ----
#pragma unroll 1
    for (int half = 0; half < 2; ++half) {
        const int jt0 = w * 4 + half * 2;
        v4i ac[2][4];
#pragma unroll
        for (int j = 0; j < 2; ++j)
#pragma unroll
            for (int c = 0; c < 4; ++c) ac[j][c] = (v4i){0, 0, 0, 0};

#pragma unroll
        for (int k = 0; k < K_; ++k) {
            // B frags: cout = cout0+ct*16+l15, ci = l4*16..+15 (16B contiguous, coalesced)
            v4i wfk[4];
#pragma unroll
            for (int ct = 0; ct < 4; ++ct)
                wfk[ct] = *(const v4i*)(Wp + (((size_t)k * COUT + cout0 + ct * 16 + l15) << 6) + (l4 << 4));

            // A frags: row pl = c0 + tile*16 + l15 + k; lane's K-slice = halfword l4 of A word.
            // Expand 16 sign bits -> 16 bytes (+1 / -1) in-register.
            v4i af[2];
#pragma unroll
            for (int j = 0; j < 2; ++j) {
                const int pg = c0 + (jt0 + j) * 16 + l15 + k;
                const uint32_t h = ap[pg * 4 + l4];
                v4i f;
#pragma unroll
                for (int d = 0; d < 4; ++d) {
                    uint32_t n  = (h >> (4 * d)) & 0xFu;
                    uint32_t tb = (n * 0x00204081u) & 0x01010101u;   // bit j -> byte j bit0
                    f[d] = (int)(0x01010101u ^ ((tb << 8) - (tb << 1)));  // ^ tb*0xFE
                }
                af[j] = f;
            }

#pragma unroll
            for (int j = 0; j < 2; ++j) {
                ac[j][0] = __builtin_amdgcn_mfma_i32_16x16x64_i8(af[j], wfk[0], ac[j][0], 0, 0, 0);
                ac[j][1] = __builtin_amdgcn_mfma_i32_16x16x64_i8(af[j], wfk[1], ac[j][1], 0, 0, 0);
                ac[j][2] = __builtin_amdgcn_mfma_i32_16x16x64_i8(af[j], wfk[2], ac[j][2], 0, 0, 0);
                ac[j][3] = __builtin_amdgcn_mfma_i32_16x16x64_i8(af[j], wfk[3], ac[j][3], 0, 0, 0);
            }
        }

        // C layout: col(cout_loc)=l15, row(c_loc)=l4*4+reg -> 4 consecutive c per lane.
        // Guard: only rows < CSTR (tail tiles beyond the pooled range are dropped).
#pragma unroll
        for (int j = 0; j < 2; ++j) {
            const int crow = (jt0 + j) * 16 + l4 * 4;
            if (crow <= CSTR - 4) {
#pragma unroll
                for (int ct = 0; ct < 4; ++ct) {
                    uint32_t p0 = ((uint32_t)ac[j][ct][0] & 0xFFFFu) | ((uint32_t)ac[j][ct][1] << 16);
                    uint32_t p1 = ((uint32_t)ac[j][ct][2] & 0xFFFFu) | ((uint32_t)ac[j][ct][3] << 16);
                    *(uint2*)(cs + (size_t)(ct * 16 + l15) * CSTR + crow) = make_uint2(p0, p1);
                }
            }
        }
    }
    __syncthreads();

    // ---- pool(7,2) + threshold. wave w owns couts w*16..w*16+15 ----
#pragma unroll 1
    for (int ci = 0; ci < 16; ++ci) {
        const int cl = w * 16 + ci;
        const int co = cout0 + cl;
        // pooled > tp  <=>  pooled >= floor(tp)+1   (pooled is an integer)
        const int Tip = (int)floorf(tp_[co]) + 1;
        const int Tim = (int)floorf(tm_[co]) + 1;
        const float psv = ps_[co], msv = ms_[co];
        const uint32_t* row = (const uint32_t*)(cs + (size_t)cl * CSTR);  // dword i = conv[2i..2i+1]
        float* op = out + ((size_t)(b * COUT + co)) * LOUT + o0;
#pragma unroll
        for (int oi = 0; oi < 2; ++oi) {
            const int o = oi * 64 + lane;
            if (o < OB && o0 + o < LOUT) {
                uint32_t d0 = row[o], d1 = row[o + 1], d2 = row[o + 2], d3 = row[o + 3];
                int a0 = (int)(short)(d0 & 0xFFFFu), a1 = ((int)d0) >> 16;
                int a2 = (int)(short)(d1 & 0xFFFFu), a3 = ((int)d1) >> 16;
                int a4 = (int)(short)(d2 & 0xFFFFu), a5 = ((int)d2) >> 16;
                int a6 = (int)(short)(d3 & 0xFFFFu);              // c = 2o+6; 2o+7 excluded
                int m = max(max(max(a0, a1), max(a2, a3)), max(max(a4, a5), a6));
                op[o] = (m >= 0) ? (m >= Tip ? psv : -psv) : (m >= Tim ? msv : -msv);
            }
        }
    }
}

extern "C" void kernel_launch(void* const* d_in, const int* in_sizes, int n_in,
                              void* d_out, int out_size, void* d_ws, size_t ws_size,
                              hipStream_t stream) {
    const float* I  = (const float*)d_in[0];
    const float* W  = (const float*)d_in[1];
    const float* tp = (const float*)d_in[2];
    const float* tm = (const float*)d_in[3];
    const float* ps = (const float*)d_in[4];
    const float* ms = (const float*)d_in[5];
    float* out = (float*)d_out;

    uint64_t* A  = (uint64_t*)d_ws;
    uint8_t*  Wp = (uint8_t*)((char*)d_ws + ((size_t)B_ * LPA + AMARGIN) * sizeof(uint64_t));

    hipLaunchKernelGGL(pack_A, dim3(B_ * 16), dim3(256), 0, stream, I, A);
    hipLaunchKernelGGL(pack_Wi8, dim3((COUT * K_ + 255) / 256), dim3(256), 0, stream, W, Wp);
    hipLaunchKernelGGL(mfma_conv_pool, dim3(NXB, 2, B_), dim3(256), 0, stream,
                       A, Wp, tp, tm, ps, ms, out);
}

// Round 5
// 602.435 us; speedup vs baseline: 1.4806x; 1.4806x over previous
//
#include <hip/hip_runtime.h>
#include <stdint.h>

#define B_    64
#define CIN   64
#define L_IN  16384
#define COUT  128
#define K_    7
#define LPAD  3
#define LPA   16416             // padded row stride for A (uint64 words per b)
#define AMARGIN 512
#define LOUT  8189              // pooled output length
#define OB    88                // pooled outputs per block
#define NXB   94                // ceil(8189/88)
#define NT    12                // c-tiles per block (3 per wave)
#define XROWS 200               // int8 X rows staged in LDS (need 198)
#define CSTR  184               // int16 conv slots per cout row (need <=183)

typedef int v4i __attribute__((ext_vector_type(4)));

// ---------------- pack A: sign bits of I along Cin into uint64 ----------------
// A[b][l]: bit ci = 1 iff value < 0. Pad positions (value -1.0) = all ones.
__global__ __launch_bounds__(256) void pack_A(const float* __restrict__ I,
                                              uint64_t* __restrict__ A) {
    int b     = blockIdx.x >> 4;     // 16 blocks per b
    int chunk = blockIdx.x & 15;
    int t     = threadIdx.x;
    int l0    = chunk * 1024 + t * 4;
    const uint32_t* Ib = (const uint32_t*)(I + (size_t)b * CIN * L_IN + l0);
    uint32_t lo0 = 0, lo1 = 0, lo2 = 0, lo3 = 0;
    uint32_t hi0 = 0, hi1 = 0, hi2 = 0, hi3 = 0;
#pragma unroll 8
    for (int ci = 0; ci < 32; ++ci) {
        uint4 v = *(const uint4*)(Ib + (size_t)ci * L_IN);
        lo0 |= (v.x >> 31) << ci;
        lo1 |= (v.y >> 31) << ci;
        lo2 |= (v.z >> 31) << ci;
        lo3 |= (v.w >> 31) << ci;
    }
#pragma unroll 8
    for (int ci = 0; ci < 32; ++ci) {
        uint4 v = *(const uint4*)(Ib + (size_t)(ci + 32) * L_IN);
        hi0 |= (v.x >> 31) << ci;
        hi1 |= (v.y >> 31) << ci;
        hi2 |= (v.z >> 31) << ci;
        hi3 |= (v.w >> 31) << ci;
    }
    uint64_t* Ab = A + (size_t)b * LPA + (LPAD + l0);
    Ab[0] = ((uint64_t)hi0 << 32) | lo0;
    Ab[1] = ((uint64_t)hi1 << 32) | lo1;
    Ab[2] = ((uint64_t)hi2 << 32) | lo2;
    Ab[3] = ((uint64_t)hi3 << 32) | lo3;
    // pad columns: p in {0,1,2, 16387,16388,16389} -> sign(-1.0) -> all ones
    if (chunk == 0 && t < 6) {
        int l = (t < 3) ? t : (L_IN + t);
        A[(size_t)b * LPA + l] = ~0ULL;
    }
}

// ---------------- pack W as int8 +/-1, layout [k][cout][ci] ----------------
__global__ __launch_bounds__(256) void pack_Wi8(const float* __restrict__ W,
                                                uint8_t* __restrict__ Wp) {
    int idx = blockIdx.x * 256 + threadIdx.x;
    if (idx >= COUT * K_) return;
    int k  = idx >> 7;        // 0..6
    int co = idx & 127;
    uint8_t* dst = Wp + ((size_t)k * COUT + co) * 64;
    uint32_t d[16];
#pragma unroll
    for (int ci4 = 0; ci4 < 16; ++ci4) {
        uint32_t dw = 0;
#pragma unroll
        for (int j = 0; j < 4; ++j) {
            int ci = ci4 * 4 + j;
            uint32_t s = __float_as_uint(W[(size_t)co * CIN * K_ + ci * K_ + k]) >> 31;
            dw |= (s ? 0xFFu : 0x01u) << (8 * j);
        }
        d[ci4] = dw;
    }
#pragma unroll
    for (int q = 0; q < 4; ++q)
        *(uint4*)(dst + q * 16) = make_uint4(d[4*q+0], d[4*q+1], d[4*q+2], d[4*q+3]);
}

// ---------------- main: i8-MFMA conv + maxpool(7,2) + threshold ----------------
// Block = 88 pooled outputs x 64 couts. LDS-staged X expand (once per row),
// k-outer MFMA loop (W frags transient, acc static) -> no spill, no demotion.
// LDS total 36.4 KB -> 4 blocks/CU.
__global__ __launch_bounds__(256, 4) void mfma_conv_pool(
    const uint64_t* __restrict__ A, const uint8_t* __restrict__ Wp,
    const float* __restrict__ tp_, const float* __restrict__ tm_,
    const float* __restrict__ ps_, const float* __restrict__ ms_,
    float* __restrict__ out)
{
    __shared__ __align__(16) uint8_t xs[XROWS * 64];   // 12800 B
    __shared__ __align__(8)  int16_t cs[64 * CSTR];    // 23552 B

    const int bx = blockIdx.x, cy = blockIdx.y, b = blockIdx.z;
    const int t = threadIdx.x;
    const int lane = t & 63, w = t >> 6;
    const int l15 = lane & 15, l4 = lane >> 4;
    const int o0 = bx * OB;
    const int c0 = 2 * o0;          // first conv position this block needs
    const int cout0 = cy * 64;

    // ---- phase 1: expand A bits -> int8 +/-1 in LDS (each row expanded ONCE) ----
    // xs[p][ci], 64B rows; 16B granule swizzled: gran = g ^ ((p>>1)&3)  (0 conflicts, r3-verified)
    const uint16_t* ap = (const uint16_t*)(A + (size_t)b * LPA);
#pragma unroll
    for (int it = 0; it < 4; ++it) {
        int idx = it * 256 + t;
        if (idx < XROWS * 4) {
            int p = idx >> 2, g = idx & 3;
            int pg = c0 + p;
            if (pg < LPA) {
                uint32_t v = ap[(size_t)pg * 4 + g];   // 16 sign bits (ci 16g..16g+15)
                uint32_t dd[4];
#pragma unroll
                for (int ni = 0; ni < 4; ++ni) {
                    uint32_t n  = (v >> (4 * ni)) & 0xFu;
                    uint32_t tb = (n * 0x00204081u) & 0x01010101u;       // bit j -> byte j bit0
                    dd[ni] = 0x01010101u ^ ((tb << 8) - (tb << 1));      // ^ tb*0xFE: 0x01/+0xFF
                }
                int gran = g ^ ((p >> 1) & 3);
                *(uint4*)(xs + p * 64 + gran * 16) = make_uint4(dd[0], dd[1], dd[2], dd[3]);
            }
        }
    }
    __syncthreads();

    // ---- phase 2: MFMA conv, k-outer. wave w owns c-tiles 3w..3w+2 ----
    v4i ac[3][4];
#pragma unroll
    for (int j = 0; j < 3; ++j)
#pragma unroll
        for (int ct = 0; ct < 4; ++ct) ac[j][ct] = (v4i){0, 0, 0, 0};

#pragma unroll
    for (int k = 0; k < K_; ++k) {
        // B frags: cout = cout0+ct*16+l15, ci = l4*16..+15 (16B contiguous)
        v4i wfk[4];
#pragma unroll
        for (int ct = 0; ct < 4; ++ct)
            wfk[ct] = *(const v4i*)(Wp + (((size_t)k * COUT + cout0 + ct * 16 + l15) << 6) + (l4 << 4));
#pragma unroll
        for (int j = 0; j < 3; ++j) {
            const int pl   = (w * 3 + j) * 16 + l15 + k;
            const int gran = l4 ^ ((pl >> 1) & 3);
            const v4i af = *(const v4i*)(xs + pl * 64 + gran * 16);
            ac[j][0] = __builtin_amdgcn_mfma_i32_16x16x64_i8(af, wfk[0], ac[j][0], 0, 0, 0);
            ac[j][1] = __builtin_amdgcn_mfma_i32_16x16x64_i8(af, wfk[1], ac[j][1], 0, 0, 0);
            ac[j][2] = __builtin_amdgcn_mfma_i32_16x16x64_i8(af, wfk[2], ac[j][2], 0, 0, 0);
            ac[j][3] = __builtin_amdgcn_mfma_i32_16x16x64_i8(af, wfk[3], ac[j][3], 0, 0, 0);
        }
    }

    // C layout: col(cout_loc)=l15, row(c_loc)=l4*4+reg -> 4 consecutive c per lane.
#pragma unroll
    for (int j = 0; j < 3; ++j) {
        const int crow = (w * 3 + j) * 16 + l4 * 4;
        if (crow <= CSTR - 4) {
#pragma unroll
            for (int ct = 0; ct < 4; ++ct) {
                uint32_t p0 = ((uint32_t)ac[j][ct][0] & 0xFFFFu) | ((uint32_t)ac[j][ct][1] << 16);
                uint32_t p1 = ((uint32_t)ac[j][ct][2] & 0xFFFFu) | ((uint32_t)ac[j][ct][3] << 16);
                *(uint2*)(cs + (size_t)(ct * 16 + l15) * CSTR + crow) = make_uint2(p0, p1);
            }
        }
    }
    __syncthreads();

    // ---- phase 3: pool(7,2) + threshold. wave w owns couts w*16..w*16+15 ----
#pragma unroll 1
    for (int ci = 0; ci < 16; ++ci) {
        const int cl = w * 16 + ci;
        const int co = cout0 + cl;
        // pooled > tp  <=>  pooled >= floor(tp)+1   (pooled is an integer)
        const int Tip = (int)floorf(tp_[co]) + 1;
        const int Tim = (int)floorf(tm_[co]) + 1;
        const float psv = ps_[co], msv = ms_[co];
        const uint32_t* row = (const uint32_t*)(cs + (size_t)cl * CSTR);  // dword i = conv[2i..2i+1]
        float* op = out + ((size_t)(b * COUT + co)) * LOUT + o0;
#pragma unroll
        for (int oi = 0; oi < 2; ++oi) {
            const int o = oi * 64 + lane;
            if (o < OB && o0 + o < LOUT) {
                uint32_t d0 = row[o], d1 = row[o + 1], d2 = row[o + 2], d3 = row[o + 3];
                int a0 = (int)(short)(d0 & 0xFFFFu), a1 = ((int)d0) >> 16;
                int a2 = (int)(short)(d1 & 0xFFFFu), a3 = ((int)d1) >> 16;
                int a4 = (int)(short)(d2 & 0xFFFFu), a5 = ((int)d2) >> 16;
                int a6 = (int)(short)(d3 & 0xFFFFu);              // c = 2o+6; 2o+7 excluded
                int m = max(max(max(a0, a1), max(a2, a3)), max(max(a4, a5), a6));
                op[o] = (m >= 0) ? (m >= Tip ? psv : -psv) : (m >= Tim ? msv : -msv);
            }
        }
    }
}

extern "C" void kernel_launch(void* const* d_in, const int* in_sizes, int n_in,
                              void* d_out, int out_size, void* d_ws, size_t ws_size,
                              hipStream_t stream) {
    const float* I  = (const float*)d_in[0];
    const float* W  = (const float*)d_in[1];
    const float* tp = (const float*)d_in[2];
    const float* tm = (const float*)d_in[3];
    const float* ps = (const float*)d_in[4];
    const float* ms = (const float*)d_in[5];
    float* out = (float*)d_out;

    uint64_t* A  = (uint64_t*)d_ws;
    uint8_t*  Wp = (uint8_t*)((char*)d_ws + ((size_t)B_ * LPA + AMARGIN) * sizeof(uint64_t));

    hipLaunchKernelGGL(pack_A, dim3(B_ * 16), dim3(256), 0, stream, I, A);
    hipLaunchKernelGGL(pack_Wi8, dim3((COUT * K_ + 255) / 256), dim3(256), 0, stream, W, Wp);
    hipLaunchKernelGGL(mfma_conv_pool, dim3(NXB, 2, B_), dim3(256), 0, stream,
                       A, Wp, tp, tm, ps, ms, out);
}

// Round 9
// 593.869 us; speedup vs baseline: 1.5020x; 1.0144x over previous
//
#include <hip/hip_runtime.h>
#include <stdint.h>

#define B_    64
#define CIN   64
#define L_IN  16384
#define COUT  128
#define K_    7
#define LPAD  3
#define LPA   16416             // padded row stride for A (uint64 words per b)
#define AMARGIN 512
#define LOUT  8189              // pooled output length
#define OB    64                // pooled outputs per block
#define NXB   128               // ceil(8189/64)
#define NT    9                 // c-tiles per block
#define XROWS 144               // int8 X rows staged in LDS
#define CSTR  138               // int16 conv slots per row: 69 dwords (ODD -> all 32 banks)

typedef int v4i __attribute__((ext_vector_type(4)));

// ---------------- pack A: sign bits of I along Cin into uint64 ----------------
// A[b][l]: bit ci = 1 iff value < 0. Pad positions (value -1.0) = all ones.
__global__ __launch_bounds__(256) void pack_A(const float* __restrict__ I,
                                              uint64_t* __restrict__ A) {
    int b     = blockIdx.x >> 4;     // 16 blocks per b
    int chunk = blockIdx.x & 15;
    int t     = threadIdx.x;
    int l0    = chunk * 1024 + t * 4;
    const uint32_t* Ib = (const uint32_t*)(I + (size_t)b * CIN * L_IN + l0);
    uint32_t lo0 = 0, lo1 = 0, lo2 = 0, lo3 = 0;
    uint32_t hi0 = 0, hi1 = 0, hi2 = 0, hi3 = 0;
#pragma unroll 8
    for (int ci = 0; ci < 32; ++ci) {
        uint4 v = *(const uint4*)(Ib + (size_t)ci * L_IN);
        lo0 |= (v.x >> 31) << ci;
        lo1 |= (v.y >> 31) << ci;
        lo2 |= (v.z >> 31) << ci;
        lo3 |= (v.w >> 31) << ci;
    }
#pragma unroll 8
    for (int ci = 0; ci < 32; ++ci) {
        uint4 v = *(const uint4*)(Ib + (size_t)(ci + 32) * L_IN);
        hi0 |= (v.x >> 31) << ci;
        hi1 |= (v.y >> 31) << ci;
        hi2 |= (v.z >> 31) << ci;
        hi3 |= (v.w >> 31) << ci;
    }
    uint64_t* Ab = A + (size_t)b * LPA + (LPAD + l0);
    Ab[0] = ((uint64_t)hi0 << 32) | lo0;
    Ab[1] = ((uint64_t)hi1 << 32) | lo1;
    Ab[2] = ((uint64_t)hi2 << 32) | lo2;
    Ab[3] = ((uint64_t)hi3 << 32) | lo3;
    // pad columns: p in {0,1,2, 16387,16388,16389} -> sign(-1.0) -> all ones
    if (chunk == 0 && t < 6) {
        int l = (t < 3) ? t : (L_IN + t);
        A[(size_t)b * LPA + l] = ~0ULL;
    }
}

// ---------------- pack W as int8 +/-1, layout [k][cout][ci] ----------------
__global__ __launch_bounds__(256) void pack_Wi8(const float* __restrict__ W,
                                                uint8_t* __restrict__ Wp) {
    int idx = blockIdx.x * 256 + threadIdx.x;
    if (idx >= COUT * K_) return;
    int k  = idx >> 7;        // 0..6
    int co = idx & 127;
    uint8_t* dst = Wp + ((size_t)k * COUT + co) * 64;
    uint32_t d[16];
#pragma unroll
    for (int ci4 = 0; ci4 < 16; ++ci4) {
        uint32_t dw = 0;
#pragma unroll
        for (int j = 0; j < 4; ++j) {
            int ci = ci4 * 4 + j;
            uint32_t s = __float_as_uint(W[(size_t)co * CIN * K_ + ci * K_ + k]) >> 31;
            dw |= (s ? 0xFFu : 0x01u) << (8 * j);
        }
        d[ci4] = dw;
    }
#pragma unroll
    for (int q = 0; q < 4; ++q)
        *(uint4*)(dst + q * 16) = make_uint4(d[4*q+0], d[4*q+1], d[4*q+2], d[4*q+3]);
}

// ---------------- main: i8-MFMA conv + maxpool(7,2) + threshold ----------------
// Block = 64 pooled outputs x 64 couts. LDS = 26880 B -> 6 blocks/CU LDS-limited
// (24 waves/CU if VGPR <= 85; round-5 measured 56). CSTR odd-dword stride ->
// conflict-free C stores. launch_bounds kept at the known-good (256,4).
__global__ __launch_bounds__(256, 4) void mfma_conv_pool(
    const uint64_t* __restrict__ A, const uint8_t* __restrict__ Wp,
    const float* __restrict__ tp_, const float* __restrict__ tm_,
    const float* __restrict__ ps_, const float* __restrict__ ms_,
    float* __restrict__ out)
{
    __shared__ __align__(16) uint8_t xs[XROWS * 64];   // 9216 B
    __shared__ __align__(8)  int16_t cs[64 * CSTR];    // 17664 B

    const int bx = blockIdx.x, cy = blockIdx.y, b = blockIdx.z;
    const int t = threadIdx.x;
    const int lane = t & 63, w = t >> 6;
    const int l15 = lane & 15, l4 = lane >> 4;
    const int o0 = bx * OB;
    const int c0 = 2 * o0;          // first conv position this block needs
    const int cout0 = cy * 64;

    // ---- phase 1: expand A bits -> int8 +/-1 in LDS (each row expanded ONCE) ----
    // xs[p][ci], 64B rows; 16B granule swizzled: gran = g ^ ((p>>1)&3)  (conflict-free)
    const uint16_t* ap = (const uint16_t*)(A + (size_t)b * LPA);
#pragma unroll
    for (int it = 0; it < 3; ++it) {
        int idx = it * 256 + t;
        if (idx < XROWS * 4) {
            int p = idx >> 2, g = idx & 3;
            int pg = c0 + p;
            if (pg < LPA) {
                uint32_t v = ap[(size_t)pg * 4 + g];   // 16 sign bits (ci 16g..16g+15)
                uint32_t dd[4];
#pragma unroll
                for (int ni = 0; ni < 4; ++ni) {
                    uint32_t n  = (v >> (4 * ni)) & 0xFu;
                    uint32_t tb = (n * 0x00204081u) & 0x01010101u;       // bit j -> byte j bit0
                    dd[ni] = 0x01010101u ^ ((tb << 8) - (tb << 1));      // ^ tb*0xFE: +1 / -1 bytes
                }
                int gran = g ^ ((p >> 1) & 3);
                *(uint4*)(xs + p * 64 + gran * 16) = make_uint4(dd[0], dd[1], dd[2], dd[3]);
            }
        }
    }
    __syncthreads();

    // ---- phase 2: MFMA conv, k-outer. wave w owns tiles [tstart, tstart+ntile) ----
    const int tstart = (w * NT) >> 2;                       // 0,2,4,6
    const int ntile  = (((w + 1) * NT) >> 2) - tstart;      // 2,2,2,3

    v4i ac[3][4];
#pragma unroll
    for (int j = 0; j < 3; ++j)
#pragma unroll
        for (int ct = 0; ct < 4; ++ct) ac[j][ct] = (v4i){0, 0, 0, 0};

#pragma unroll
    for (int k = 0; k < K_; ++k) {
        // B frags: cout = cout0+ct*16+l15, ci = l4*16..+15 (16B contiguous)
        v4i wfk[4];
#pragma unroll
        for (int ct = 0; ct < 4; ++ct)
            wfk[ct] = *(const v4i*)(Wp + (((size_t)k * COUT + cout0 + ct * 16 + l15) << 6) + (l4 << 4));
#pragma unroll
        for (int j = 0; j < 3; ++j) {
            if (j < ntile) {
                int pl = (tstart + j) * 16 + l15 + k;
                // tile 8's top rows exceed the staged window; their results are
                // dropped by the crow-guard below -> clamp the address, keep it in xs
                pl = min(pl, XROWS - 1);
                const int gran = l4 ^ ((pl >> 1) & 3);
                const v4i af = *(const v4i*)(xs + pl * 64 + gran * 16);
                ac[j][0] = __builtin_amdgcn_mfma_i32_16x16x64_i8(af, wfk[0], ac[j][0], 0, 0, 0);
                ac[j][1] = __builtin_amdgcn_mfma_i32_16x16x64_i8(af, wfk[1], ac[j][1], 0, 0, 0);
                ac[j][2] = __builtin_amdgcn_mfma_i32_16x16x64_i8(af, wfk[2], ac[j][2], 0, 0, 0);
                ac[j][3] = __builtin_amdgcn_mfma_i32_16x16x64_i8(af, wfk[3], ac[j][3], 0, 0, 0);
            }
        }
    }

    // C layout: col(cout_loc)=l15, row(c_loc)=l4*4+reg -> 4 consecutive c per lane.
    // Guard drops rows > 134 (tail of tile 8), which are exactly the clamped/garbage ones.
#pragma unroll
    for (int j = 0; j < 3; ++j) {
        if (j < ntile) {
            const int crow = (tstart + j) * 16 + l4 * 4;
            if (crow <= CSTR - 4) {
#pragma unroll
                for (int ct = 0; ct < 4; ++ct) {
                    uint32_t p0 = ((uint32_t)ac[j][ct][0] & 0xFFFFu) | ((uint32_t)ac[j][ct][1] << 16);
                    uint32_t p1 = ((uint32_t)ac[j][ct][2] & 0xFFFFu) | ((uint32_t)ac[j][ct][3] << 16);
                    *(uint2*)(cs + (size_t)(ct * 16 + l15) * CSTR + crow) = make_uint2(p0, p1);
                }
            }
        }
    }
    __syncthreads();

    // ---- phase 3: pool(7,2) + threshold. wave w owns couts w*16..w*16+15, o = lane ----
    const int o = lane;
    const bool valid = (o0 + o) < LOUT;
#pragma unroll 1
    for (int ci = 0; ci < 16; ++ci) {
        const int cl = w * 16 + ci;
        const int co = cout0 + cl;
        // pooled > tp  <=>  pooled >= floor(tp)+1   (pooled is an integer)
        const int Tip = (int)floorf(tp_[co]) + 1;
        const int Tim = (int)floorf(tm_[co]) + 1;
        const float psv = ps_[co], msv = ms_[co];
        const uint32_t* row = (const uint32_t*)(cs + (size_t)cl * CSTR);  // dword i = conv[2i..2i+1]
        if (valid) {
            uint32_t d0 = row[o], d1 = row[o + 1], d2 = row[o + 2], d3 = row[o + 3];
            int a0 = (int)(short)(d0 & 0xFFFFu), a1 = ((int)d0) >> 16;
            int a2 = (int)(short)(d1 & 0xFFFFu), a3 = ((int)d1) >> 16;
            int a4 = (int)(short)(d2 & 0xFFFFu), a5 = ((int)d2) >> 16;
            int a6 = (int)(short)(d3 & 0xFFFFu);              // c = 2o+6; 2o+7 excluded
            int m = max(max(max(a0, a1), max(a2, a3)), max(max(a4, a5), a6));
            out[((size_t)(b * COUT + co)) * LOUT + o0 + o] =
                (m >= 0) ? (m >= Tip ? psv : -psv) : (m >= Tim ? msv : -msv);
        }
    }
}

extern "C" void kernel_launch(void* const* d_in, const int* in_sizes, int n_in,
                              void* d_out, int out_size, void* d_ws, size_t ws_size,
                              hipStream_t stream) {
    const float* I  = (const float*)d_in[0];
    const float* W  = (const float*)d_in[1];
    const float* tp = (const float*)d_in[2];
    const float* tm = (const float*)d_in[3];
    const float* ps = (const float*)d_in[4];
    const float* ms = (const float*)d_in[5];
    float* out = (float*)d_out;

    uint64_t* A  = (uint64_t*)d_ws;
    uint8_t*  Wp = (uint8_t*)((char*)d_ws + ((size_t)B_ * LPA + AMARGIN) * sizeof(uint64_t));

    hipLaunchKernelGGL(pack_A, dim3(B_ * 16), dim3(256), 0, stream, I, A);
    hipLaunchKernelGGL(pack_Wi8, dim3((COUT * K_ + 255) / 256), dim3(256), 0, stream, W, Wp);
    hipLaunchKernelGGL(mfma_conv_pool, dim3(NXB, 2, B_), dim3(256), 0, stream,
                       A, Wp, tp, tm, ps, ms, out);
}